// Round 12
// baseline (355.548 us; speedup 1.0000x reference)
//
#include <hip/hip_runtime.h>

#define ATT_SLOPE 0.2f
#define ACT_SLOPE 0.01f

typedef _Float16 half8  __attribute__((ext_vector_type(8)));
typedef _Float16 half2v __attribute__((ext_vector_type(2)));
typedef float    floatx4 __attribute__((ext_vector_type(4)));

#if defined(__has_builtin)
#if __has_builtin(__builtin_amdgcn_fdot2)
#define HAVE_FDOT2 1
#endif
#endif

__device__ __forceinline__ float lrelu(float v, float s) {
    return fmaxf(v, v * s);
}

__device__ __forceinline__ half2v lrelu2(half2v m) {
    half2v t = m * (_Float16)ATT_SLOPE;
    return __builtin_elementwise_max(m, t);
}

__device__ __forceinline__ float dot2(half2v a, half2v b, float c) {
#ifdef HAVE_FDOT2
    return __builtin_amdgcn_fdot2(a, b, c, false);
#else
    return c + (float)a[0] * (float)b[0] + (float)a[1] * (float)b[1];
#endif
}

// ---------------- CSR build (edges grouped by dst, self loops appended) ----------------

// count + stable rank within dst. Standalone (no LDS) at max occupancy (R10 lesson).
__global__ __launch_bounds__(256) void k_count_rank(const int* __restrict__ ei, int E, int N,
                                                    int* __restrict__ deg,
                                                    int* __restrict__ rank) {
    int i = blockIdx.x * 256 + threadIdx.x;
    int total = E + N;
    if (i >= total) return;
    int dst = (i < E) ? ei[E + i] : (i - E);
    rank[i] = atomicAdd(&deg[dst], 1);
}

__global__ __launch_bounds__(256) void k_scan_block(const int* __restrict__ deg, int n,
                                                    int* __restrict__ rp1, int* __restrict__ bsum) {
    __shared__ int s[256];
    int tid = threadIdx.x;
    int i = blockIdx.x * 256 + tid;
    s[tid] = (i < n) ? deg[i] : 0;
    __syncthreads();
    for (int off = 1; off < 256; off <<= 1) {
        int t = (tid >= off) ? s[tid - off] : 0;
        __syncthreads();
        s[tid] += t;
        __syncthreads();
    }
    if (i < n) rp1[i] = s[tid];
    if (tid == 255) bsum[blockIdx.x] = s[255];
}

// merged bsum-scan + add: each block redundantly reduces bsum[0..blockIdx) in LDS
// (nbN <= 256 guaranteed for N <= 65536).
__global__ __launch_bounds__(256) void k_scan_add(int* __restrict__ rowptr,
                                                  const int* __restrict__ bsum, int n) {
    __shared__ int s[256];
    int tid = threadIdx.x, bid = blockIdx.x;
    s[tid] = (tid < bid) ? bsum[tid] : 0;
    __syncthreads();
    for (int off = 128; off > 0; off >>= 1) {
        if (tid < off) s[tid] += s[tid + off];
        __syncthreads();
    }
    int boff = s[0];
    int i = bid * 256 + tid;
    if (i < n) rowptr[i + 1] += boff;
    if (i == 0) rowptr[0] = 0;
}

// -- weight hi/lo fp16 split encode + gsum zero + deg zero (one launch, runs FIRST) --

__global__ __launch_bounds__(256) void k_encode_w(const float* __restrict__ w1l,
                                                  const float* __restrict__ w1r,
                                                  const float* __restrict__ w2l,
                                                  const float* __restrict__ w2r,
                                                  _Float16* __restrict__ W1h,
                                                  _Float16* __restrict__ W1lo,
                                                  _Float16* __restrict__ W2h,
                                                  _Float16* __restrict__ W2lo,
                                                  float* __restrict__ gsum, int gn,
                                                  int* __restrict__ deg, int n) {
    int i = blockIdx.x * 256 + threadIdx.x;   // 0 .. 49151 + gn + n
    if (i >= 49152 + gn + n) return;
    if (i >= 49152 + gn) {                     // zero deg (replaces hipMemsetAsync launch)
        deg[i - 49152 - gn] = 0;
        return;
    }
    if (i >= 49152) {                          // zero the pool accumulator each launch
        gsum[i - 49152] = 0.f;
        return;
    }
    float v;
    _Float16 *ph, *pl;
    int idx;
    if (i < 32768) {
        idx = i;
        v = (i < 16384) ? w1l[i] : w1r[i - 16384];
        ph = W1h; pl = W1lo;
    } else {
        int j = i - 32768;
        idx = j;
        v = (j < 8192) ? w2l[j] : w2r[j - 8192];
        ph = W2h; pl = W2lo;
    }
    _Float16 h = (_Float16)v;
    ph[idx] = h;
    pl[idx] = (_Float16)(v - (float)h);
}

// ------------- MFMA split-f16 dual linear, W direct-from-global (no LDS, no barriers) -----
// W (64-128 KB) is L2-resident with full cross-block reuse; each lane loads its 16B
// B-fragment directly. Removes 2 barriers x 4 K-steps + all staging LDS traffic, and
// frees the fused kernel's scatter tail-blocks from a 40KB LDS allocation.
// MFMA sequence identical to the staged version -> bit-identical numerics.

template <int COUT, bool IN_F32>
__device__ __forceinline__ void gemm_body(int bid, int tid,
                                          const float* __restrict__ Af,
                                          const _Float16* __restrict__ Ahi,
                                          const _Float16* __restrict__ Alo, int n_rows,
                                          const _Float16* __restrict__ Whi,
                                          const _Float16* __restrict__ Wlo,
                                          const float* __restrict__ B0,
                                          const float* __restrict__ B1,
                                          _Float16* __restrict__ out) {
    constexpr int NT = COUT / 16;
    const int lane = tid & 63, wv = tid >> 6;   // wv in [0,4)
    const int m = lane & 15, q = lane >> 4;
    const long row0 = ((long)bid * 4 + wv) * 16;
    if (row0 >= n_rows) return;                 // wave-uniform (n_rows % 16 == 0)
    const long arow = row0 + m;

    floatx4 acc[NT] = {};
    for (int kk = 0; kk < 128; kk += 32) {
        half8 ah, al;
        if constexpr (IN_F32) {
            float4 a0 = *(const float4*)&Af[(size_t)arow * 128 + kk + q * 8];
            float4 a1 = *(const float4*)&Af[(size_t)arow * 128 + kk + q * 8 + 4];
            float av[8] = {a0.x, a0.y, a0.z, a0.w, a1.x, a1.y, a1.z, a1.w};
            #pragma unroll
            for (int x = 0; x < 8; ++x) {
                ah[x] = (_Float16)av[x];
                al[x] = (_Float16)(av[x] - (float)ah[x]);
            }
        } else {
            ah = *(const half8*)&Ahi[(size_t)arow * 128 + kk + q * 8];
            al = *(const half8*)&Alo[(size_t)arow * 128 + kk + q * 8];
        }
        const _Float16* wh = &Whi[(size_t)m * 128 + kk + q * 8];
        const _Float16* wl = &Wlo[(size_t)m * 128 + kk + q * 8];
        #pragma unroll
        for (int nt = 0; nt < NT; ++nt) {
            half8 bh = *(const half8*)&wh[(size_t)nt * 16 * 128];
            half8 bl = *(const half8*)&wl[(size_t)nt * 16 * 128];
            acc[nt] = __builtin_amdgcn_mfma_f32_16x16x32_f16(ah, bh, acc[nt], 0, 0, 0);
            acc[nt] = __builtin_amdgcn_mfma_f32_16x16x32_f16(al, bh, acc[nt], 0, 0, 0);
            acc[nt] = __builtin_amdgcn_mfma_f32_16x16x32_f16(ah, bl, acc[nt], 0, 0, 0);
        }
    }
    // C/D layout: col = lane&15, row = (lane>>4)*4 + reg
    #pragma unroll
    for (int nt = 0; nt < NT; ++nt) {
        int col = nt * 16 + m;
        float b = (col < COUT / 2) ? B0[col] : B1[col - COUT / 2];
        #pragma unroll
        for (int r = 0; r < 4; ++r) {
            long grow = row0 + q * 4 + r;
            out[(size_t)grow * COUT + col] = (_Float16)(acc[nt][r] + b);
        }
    }
}

// Fused: blocks [0,gB) run gemm1 (COUT=256, fp32 in); blocks [gB,..) run single-pass
// scatter. Now LDS-free for both halves.
__global__ __launch_bounds__(256) void k_gemm1_scatter(const float* __restrict__ x,
                                                       const _Float16* __restrict__ W1h,
                                                       const _Float16* __restrict__ W1lo,
                                                       const float* __restrict__ B0,
                                                       const float* __restrict__ B1,
                                                       _Float16* __restrict__ buf1, int n_rows,
                                                       const int* __restrict__ ei, int E,
                                                       const int* __restrict__ rowptr,
                                                       const int* __restrict__ rank,
                                                       int* __restrict__ adj, int gB) {
    const int bid = blockIdx.x, tid = threadIdx.x;
    if (bid < gB) {
        gemm_body<256, true>(bid, tid, x, nullptr, nullptr, n_rows,
                             W1h, W1lo, B0, B1, buf1);
    } else {
        int i = (bid - gB) * 256 + tid;
        int T = E + n_rows;
        if (i < T) {
            int dst = (i < E) ? ei[E + i] : (i - E);
            int src = (i < E) ? ei[i] : dst;
            adj[rowptr[dst] + rank[i]] = src;
        }
    }
}

template <int COUT, bool IN_F32>
__global__ __launch_bounds__(256) void gemm_mfma(const float* __restrict__ Af,
                                                 const _Float16* __restrict__ Ahi,
                                                 const _Float16* __restrict__ Alo, int n_rows,
                                                 const _Float16* __restrict__ Whi,
                                                 const _Float16* __restrict__ Wlo,
                                                 const float* __restrict__ B0,
                                                 const float* __restrict__ B1,
                                                 _Float16* __restrict__ out) {
    gemm_body<COUT, IN_F32>(blockIdx.x, threadIdx.x, Af, Ahi, Alo, n_rows,
                            Whi, Wlo, B0, B1, out);
}

// ---------------- fused GATv2 conv1 edge phase (heads=2, ch=64) ----------------
// R7-verbatim: inner loop R0 body, 128-thread blocks = 2 nodes/block. Do not touch.

__global__ __launch_bounds__(128) void conv1_fused(const _Float16* __restrict__ buf,
                                                   const int* __restrict__ rowptr,
                                                   const int* __restrict__ adj,
                                                   const float* __restrict__ att,   // [128]
                                                   const float* __restrict__ bias,  // [128]
                                                   _Float16* __restrict__ h1hi,
                                                   _Float16* __restrict__ h1lo, int n) {
    __shared__ _Float16 sxl[2][16][136];   // 272B row stride, 16B-aligned
    __shared__ _Float16 sxr[2][128];
    __shared__ float    sw[2][2][16];
    __shared__ _Float16 satt[128];
    const int tid = threadIdx.x, lane = tid & 63, wv = tid >> 6;
    satt[tid] = (_Float16)att[tid];        // 128 threads cover [128]
    __syncthreads();                        // all threads reach; no block barriers after this
    int node = blockIdx.x * 2 + wv;
    if (node >= n) return;

    const int jlane = lane & 15;           // edge slot within chunk
    const int grp = lane >> 4;             // channel quarter 0..3 (0,1->head0; 2,3->head1)
    const int chq = grp * 32;
    const int head = grp >> 1;
    const int wselg = lane >> 5;           // phase-B head for channels lane*2 (0..127)
    if (lane < 16)
        *(half8*)&sxr[wv][lane * 8] = *(const half8*)&buf[(size_t)node * 256 + 128 + lane * 8];
    asm volatile("s_waitcnt lgkmcnt(0)" ::: "memory");

    const int s = rowptr[node], e = rowptr[node + 1];
    float2 accA = {0.f, 0.f}, accB = {0.f, 0.f};
    float denA = 0.f, denB = 0.f;
    for (int c0 = s; c0 < e; c0 += 16) {
        const int cnt = min(16, e - c0);
        float sacc0 = 0.f, sacc1 = 0.f;
        if (jlane < cnt) {
            int src = adj[c0 + jlane];
            const _Float16* xlp = &buf[(size_t)src * 256 + chq];
            #pragma unroll
            for (int k = 0; k < 4; ++k) {
                half8 l = *(const half8*)&xlp[k * 8];
                half8 r = *(const half8*)&sxr[wv][chq + k * 8];
                half8 a = *(const half8*)&satt[chq + k * 8];
                *(half8*)&sxl[wv][jlane][chq + k * 8] = l;
                float* sp = (k & 1) ? &sacc1 : &sacc0;
                #pragma unroll
                for (int p = 0; p < 4; ++p) {
                    half2v lp = {l[2 * p], l[2 * p + 1]};
                    half2v rp = {r[2 * p], r[2 * p + 1]};
                    half2v ap = {a[2 * p], a[2 * p + 1]};
                    *sp = dot2(lrelu2(lp + rp), ap, *sp);
                }
            }
        }
        float sacc = sacc0 + sacc1;
        float efull = sacc + __shfl_xor(sacc, 16);   // combine the two quarters of this head
        if ((grp & 1) == 0 && jlane < cnt) sw[wv][head][jlane] = __expf(efull);
        asm volatile("s_waitcnt lgkmcnt(0)" ::: "memory");
        // phase B: lane -> channels (2*lane, 2*lane+1); its head's weights; 2-way unroll
        int j = 0;
        for (; j + 1 < cnt; j += 2) {
            float w0 = sw[wv][wselg][j], w1 = sw[wv][wselg][j + 1];
            half2v v0 = *(const half2v*)&sxl[wv][j][lane * 2];
            half2v v1 = *(const half2v*)&sxl[wv][j + 1][lane * 2];
            accA.x += w0 * (float)v0[0]; accA.y += w0 * (float)v0[1]; denA += w0;
            accB.x += w1 * (float)v1[0]; accB.y += w1 * (float)v1[1]; denB += w1;
        }
        if (j < cnt) {
            float w0 = sw[wv][wselg][j];
            half2v v0 = *(const half2v*)&sxl[wv][j][lane * 2];
            accA.x += w0 * (float)v0[0]; accA.y += w0 * (float)v0[1]; denA += w0;
        }
        asm volatile("s_waitcnt lgkmcnt(0)" ::: "memory");  // drain reads before next overwrite
    }
    float inv = 1.f / (denA + denB);
    float2 b = *(const float2*)&bias[lane * 2];
    float ox = lrelu((accA.x + accB.x) * inv + b.x, ACT_SLOPE);
    float oy = lrelu((accA.y + accB.y) * inv + b.y, ACT_SLOPE);
    half2v hv, lv;
    hv[0] = (_Float16)ox; lv[0] = (_Float16)(ox - (float)hv[0]);
    hv[1] = (_Float16)oy; lv[1] = (_Float16)(oy - (float)hv[1]);
    *(half2v*)&h1hi[(size_t)node * 128 + lane * 2] = hv;
    *(half2v*)&h1lo[(size_t)node * 128 + lane * 2] = lv;
}

// ---------------- fused GATv2 conv2 edge phase (heads=1, ch=64) ----------------
// R9-verbatim (chunk=16, VGPR 24, measured 51us; chunk=32 measured 53 in R11 -> reverted).
// Pool accumulation fused into epilogue (atomicAdd into gsum[G][64]).

__global__ __launch_bounds__(128) void conv2_fused(const _Float16* __restrict__ buf,
                                                   const int* __restrict__ rowptr,
                                                   const int* __restrict__ adj,
                                                   const float* __restrict__ att,    // [64]
                                                   const float* __restrict__ bias,   // [64]
                                                   const int* __restrict__ batch,    // [N]
                                                   float* __restrict__ gsum, int n) {
    __shared__ _Float16 sxl[2][16][72];    // 144B row stride, 16B-aligned
    __shared__ _Float16 sxr[2][64];
    __shared__ float    sw[2][16];
    __shared__ _Float16 satt[64];
    const int tid = threadIdx.x, lane = tid & 63, wv = tid >> 6;
    if (tid < 64) satt[tid] = (_Float16)att[tid];
    __syncthreads();
    int node = blockIdx.x * 2 + wv;
    if (node >= n) return;

    const int jlane = lane & 15;
    const int grp = lane >> 4;             // channel quarter 0..3 (16 ch each)
    const int chq = grp * 16;
    if (lane < 8)
        *(half8*)&sxr[wv][lane * 8] = *(const half8*)&buf[(size_t)node * 128 + 64 + lane * 8];
    asm volatile("s_waitcnt lgkmcnt(0)" ::: "memory");

    const int s = rowptr[node], e = rowptr[node + 1];
    float accA = 0.f, accB = 0.f, denA = 0.f, denB = 0.f;
    for (int c0 = s; c0 < e; c0 += 16) {
        const int cnt = min(16, e - c0);
        float sacc = 0.f;
        if (jlane < cnt) {
            int src = adj[c0 + jlane];
            const _Float16* xlp = &buf[(size_t)src * 128 + chq];
            #pragma unroll
            for (int k = 0; k < 2; ++k) {
                half8 l = *(const half8*)&xlp[k * 8];
                half8 r = *(const half8*)&sxr[wv][chq + k * 8];
                half8 a = *(const half8*)&satt[chq + k * 8];
                *(half8*)&sxl[wv][jlane][chq + k * 8] = l;
                #pragma unroll
                for (int p = 0; p < 4; ++p) {
                    half2v lp = {l[2 * p], l[2 * p + 1]};
                    half2v rp = {r[2 * p], r[2 * p + 1]};
                    half2v ap = {a[2 * p], a[2 * p + 1]};
                    sacc = dot2(lrelu2(lp + rp), ap, sacc);
                }
            }
        }
        float s1 = sacc + __shfl_xor(sacc, 16);
        float efull = s1 + __shfl_xor(s1, 32);
        if (grp == 0 && jlane < cnt) sw[wv][jlane] = __expf(efull);
        asm volatile("s_waitcnt lgkmcnt(0)" ::: "memory");
        int j = 0;
        for (; j + 1 < cnt; j += 2) {
            float w0 = sw[wv][j], w1 = sw[wv][j + 1];
            accA += w0 * (float)sxl[wv][j][lane];     denA += w0;
            accB += w1 * (float)sxl[wv][j + 1][lane]; denB += w1;
        }
        if (j < cnt) {
            float w0 = sw[wv][j];
            accA += w0 * (float)sxl[wv][j][lane];
            denA += w0;
        }
        asm volatile("s_waitcnt lgkmcnt(0)" ::: "memory");
    }
    float val = lrelu((accA + accB) / (denA + denB) + bias[lane], ACT_SLOPE);
    atomicAdd(&gsum[(size_t)batch[node] * 64 + lane], val);
}

// ---------------- pooled MLP head: gsum/cnt -> fc1 -> lrelu -> fc2 ----------------

__device__ __forceinline__ int lower_bound(const int* a, int n, int v) {
    int lo = 0, hi = n;
    while (lo < hi) { int mid = (lo + hi) >> 1; if (a[mid] < v) lo = mid + 1; else hi = mid; }
    return lo;
}

__global__ __launch_bounds__(256) void pool_mlp(const float* __restrict__ gsum,  // [G,64]
                                                const int* __restrict__ batch,   // [N] sorted
                                                const float* __restrict__ fc1_w,
                                                const float* __restrict__ fc1_b,
                                                const float* __restrict__ fc2_w,
                                                const float* __restrict__ fc2_b,
                                                float* __restrict__ out, int n) {
    const int g = blockIdx.x;
    const int tid = threadIdx.x;
    __shared__ float pooled[64];
    __shared__ float hmid[64];

    int lo = lower_bound(batch, n, g);
    int hi = lower_bound(batch, n, g + 1);
    float inv = 1.f / (float)max(hi - lo, 1);

    if (tid < 64) pooled[tid] = gsum[(size_t)g * 64 + tid] * inv;
    __syncthreads();
    if (tid < 64) {
        float acc = fc1_b[tid];
        const float* w = &fc1_w[(size_t)tid * 64];
        #pragma unroll
        for (int k = 0; k < 64; ++k) acc += pooled[k] * w[k];
        hmid[tid] = lrelu(acc, ACT_SLOPE);
    }
    __syncthreads();
    for (int o = tid; o < 768; o += 256) {
        float acc = fc2_b[o];
        const float* w = &fc2_w[(size_t)o * 64];
        #pragma unroll
        for (int k = 0; k < 64; ++k) acc += hmid[k] * w[k];
        out[(size_t)g * 768 + o] = acc;
    }
}

// ---------------- launch ----------------

extern "C" void kernel_launch(void* const* d_in, const int* in_sizes, int n_in,
                              void* d_out, int out_size, void* d_ws, size_t ws_size,
                              hipStream_t stream) {
    const float* x     = (const float*)d_in[0];
    const int*   ei    = (const int*)d_in[1];
    const int*   batch = (const int*)d_in[2];
    const float* w1_l  = (const float*)d_in[3];
    const float* b1_l  = (const float*)d_in[4];
    const float* w1_r  = (const float*)d_in[5];
    const float* b1_r  = (const float*)d_in[6];
    const float* att1  = (const float*)d_in[7];
    const float* bias1 = (const float*)d_in[8];
    const float* w2_l  = (const float*)d_in[9];
    const float* b2_l  = (const float*)d_in[10];
    const float* w2_r  = (const float*)d_in[11];
    const float* b2_r  = (const float*)d_in[12];
    const float* att2  = (const float*)d_in[13];
    const float* bias2 = (const float*)d_in[14];
    const float* fc1_w = (const float*)d_in[15];
    const float* fc1_b = (const float*)d_in[16];
    const float* fc2_w = (const float*)d_in[17];
    const float* fc2_b = (const float*)d_in[18];
    float* out = (float*)d_out;

    const int N = in_sizes[2];
    const int E = in_sizes[1] / 2;
    const int T = E + N;
    const int G = out_size / 768;

    char* ws = (char*)d_ws;
    size_t off = 0;
    auto alloc = [&](size_t bytes) -> void* {
        void* p = ws + off;
        off = (off + bytes + 255) & ~(size_t)255;
        return p;
    };
    int*      deg    = (int*)alloc((size_t)N * 4);
    int*      rowptr = (int*)alloc((size_t)(N + 1) * 4);
    int*      rank   = (int*)alloc((size_t)T * 4);
    int*      bsum   = (int*)alloc(1024);
    int*      adj    = (int*)alloc((size_t)T * 4);
    _Float16* h1hi   = (_Float16*)alloc((size_t)N * 128 * 2);
    _Float16* h1lo   = (_Float16*)alloc((size_t)N * 128 * 2);
    _Float16* W1h    = (_Float16*)alloc(32768 * 2);
    _Float16* W1lo   = (_Float16*)alloc(32768 * 2);
    _Float16* W2h    = (_Float16*)alloc(16384 * 2);
    _Float16* W2lo   = (_Float16*)alloc(16384 * 2);
    float*    gsum   = (float*)alloc((size_t)G * 64 * 4);
    _Float16* buf1   = (_Float16*)alloc((size_t)N * 256 * 2);
    // lifetime aliasing: buf1 (N*512 B) dead after conv1_fused -> buf2 fp16 [N,128]
    // (N*256 B) reuses the first half.
    _Float16* buf2 = buf1;

    const int nbN  = (N + 255) / 256;           // <= 256 required by k_scan_add (N <= 65536)
    const int nbT  = (T + 255) / 256;
    const int mfmG = (N / 16 + 3) / 4;          // 16-row tiles, 4 per 256-thread block
    const int edgG = (N + 1) / 2;               // 2 nodes per 128-thread block
    const int encG = (49152 + G * 64 + N + 255) / 256;

    // ---- weight encode + gsum zero + deg zero (independent; runs first) ----
    k_encode_w<<<encG, 256, 0, stream>>>(w1_l, w1_r, w2_l, w2_r,
                                         W1h, W1lo, W2h, W2lo, gsum, G * 64, deg, N);

    // ---- CSR build ----
    k_count_rank<<<nbT, 256, 0, stream>>>(ei, E, N, deg, rank);
    k_scan_block<<<nbN, 256, 0, stream>>>(deg, N, rowptr + 1, bsum);
    k_scan_add<<<nbN, 256, 0, stream>>>(rowptr, bsum, N);

    // ---- gemm1 (blocks [0,mfmG)) fused with single-pass scatter (blocks [mfmG,..)) ----
    k_gemm1_scatter<<<mfmG + nbT, 256, 0, stream>>>(x, W1h, W1lo, b1_l, b1_r, buf1, N,
                                                    ei, E, rowptr, rank, adj, mfmG);

    // ---- conv1 ----
    conv1_fused<<<edgG, 128, 0, stream>>>(buf1, rowptr, adj, att1, bias1, h1hi, h1lo, N);

    // ---- conv2 (pool accumulation fused into epilogue) ----
    gemm_mfma<128, false><<<mfmG, 256, 0, stream>>>(nullptr, h1hi, h1lo, N,
                                                    W2h, W2lo, b2_l, b2_r, buf2);
    conv2_fused<<<edgG, 128, 0, stream>>>(buf2, rowptr, adj, att2, bias2, batch, gsum, N);

    // ---- MLP head ----
    pool_mlp<<<G, 256, 0, stream>>>(gsum, batch, fc1_w, fc1_b, fc2_w, fc2_b, out, N);
}

// Round 13
// 303.671 us; speedup vs baseline: 1.1708x; 1.1708x over previous
//
#include <hip/hip_runtime.h>

#define ATT_SLOPE 0.2f
#define ACT_SLOPE 0.01f

typedef _Float16 half8  __attribute__((ext_vector_type(8)));
typedef _Float16 half2v __attribute__((ext_vector_type(2)));
typedef float    floatx4 __attribute__((ext_vector_type(4)));

#if defined(__has_builtin)
#if __has_builtin(__builtin_amdgcn_fdot2)
#define HAVE_FDOT2 1
#endif
#endif

__device__ __forceinline__ float lrelu(float v, float s) {
    return fmaxf(v, v * s);
}

__device__ __forceinline__ half2v lrelu2(half2v m) {
    half2v t = m * (_Float16)ATT_SLOPE;
    return __builtin_elementwise_max(m, t);
}

__device__ __forceinline__ float dot2(half2v a, half2v b, float c) {
#ifdef HAVE_FDOT2
    return __builtin_amdgcn_fdot2(a, b, c, false);
#else
    return c + (float)a[0] * (float)b[0] + (float)a[1] * (float)b[1];
#endif
}

// ---------------- CSR build (edges grouped by dst, self loops appended) ----------------

// count + stable rank within dst. Standalone (no LDS!) so its ~3300 blocks run at max
// occupancy — R10 showed fusing this with the 40KB-LDS gemm collapses it to 25% occ.
__global__ __launch_bounds__(256) void k_count_rank(const int* __restrict__ ei, int E, int N,
                                                    int* __restrict__ deg,
                                                    int* __restrict__ rank) {
    int i = blockIdx.x * 256 + threadIdx.x;
    int total = E + N;
    if (i >= total) return;
    int dst = (i < E) ? ei[E + i] : (i - E);
    rank[i] = atomicAdd(&deg[dst], 1);
}

__global__ __launch_bounds__(256) void k_scan_block(const int* __restrict__ deg, int n,
                                                    int* __restrict__ rp1, int* __restrict__ bsum) {
    __shared__ int s[256];
    int tid = threadIdx.x;
    int i = blockIdx.x * 256 + tid;
    s[tid] = (i < n) ? deg[i] : 0;
    __syncthreads();
    for (int off = 1; off < 256; off <<= 1) {
        int t = (tid >= off) ? s[tid - off] : 0;
        __syncthreads();
        s[tid] += t;
        __syncthreads();
    }
    if (i < n) rp1[i] = s[tid];
    if (tid == 255) bsum[blockIdx.x] = s[255];
}

// merged bsum-scan + add: each block redundantly reduces bsum[0..blockIdx) in LDS
// (nbN <= 256 guaranteed for N <= 65536).
__global__ __launch_bounds__(256) void k_scan_add(int* __restrict__ rowptr,
                                                  const int* __restrict__ bsum, int n) {
    __shared__ int s[256];
    int tid = threadIdx.x, bid = blockIdx.x;
    s[tid] = (tid < bid) ? bsum[tid] : 0;
    __syncthreads();
    for (int off = 128; off > 0; off >>= 1) {
        if (tid < off) s[tid] += s[tid + off];
        __syncthreads();
    }
    int boff = s[0];
    int i = bid * 256 + tid;
    if (i < n) rowptr[i + 1] += boff;
    if (i == 0) rowptr[0] = 0;
}

// -- weight hi/lo fp16 split encode + gsum zero + deg zero (one launch, runs FIRST) --

__global__ __launch_bounds__(256) void k_encode_w(const float* __restrict__ w1l,
                                                  const float* __restrict__ w1r,
                                                  const float* __restrict__ w2l,
                                                  const float* __restrict__ w2r,
                                                  _Float16* __restrict__ W1h,
                                                  _Float16* __restrict__ W1lo,
                                                  _Float16* __restrict__ W2h,
                                                  _Float16* __restrict__ W2lo,
                                                  float* __restrict__ gsum, int gn,
                                                  int* __restrict__ deg, int n) {
    int i = blockIdx.x * 256 + threadIdx.x;   // 0 .. 49151 + gn + n
    if (i >= 49152 + gn + n) return;
    if (i >= 49152 + gn) {                     // zero deg (replaces hipMemsetAsync launch)
        deg[i - 49152 - gn] = 0;
        return;
    }
    if (i >= 49152) {                          // zero the pool accumulator each launch
        gsum[i - 49152] = 0.f;
        return;
    }
    float v;
    _Float16 *ph, *pl;
    int idx;
    if (i < 32768) {
        idx = i;
        v = (i < 16384) ? w1l[i] : w1r[i - 16384];
        ph = W1h; pl = W1lo;
    } else {
        int j = i - 32768;
        idx = j;
        v = (j < 8192) ? w2l[j] : w2r[j - 8192];
        ph = W2h; pl = W2lo;
    }
    _Float16 h = (_Float16)v;
    ph[idx] = h;
    pl[idx] = (_Float16)(v - (float)h);
}

// ------------- MFMA split-f16 dual linear, 256-thread blocks (4 waves, 64 rows) -------------
// LDS-staged W (R12 proved direct-from-global W costs 76-81us: per-lane VMEM issue +
// VGPR 80 + 25% occupancy; staging reads W once per block and serves fragments from LDS).

template <int COUT, bool IN_F32>
__device__ __forceinline__ void gemm_body(int bid, int tid,
                                          _Float16 (*sWh)[40], _Float16 (*sWl)[40],
                                          const float* __restrict__ Af,
                                          const _Float16* __restrict__ Ahi,
                                          const _Float16* __restrict__ Alo, int n_rows,
                                          const _Float16* __restrict__ Whi,
                                          const _Float16* __restrict__ Wlo,
                                          const float* __restrict__ B0,
                                          const float* __restrict__ B1,
                                          _Float16* __restrict__ out) {
    constexpr int NT = COUT / 16;
    const int lane = tid & 63, wv = tid >> 6;   // wv in [0,4)
    const int m = lane & 15, q = lane >> 4;
    const long row0 = ((long)bid * 4 + wv) * 16;
    const bool active = row0 < n_rows;          // wave-uniform (n_rows % 16 == 0)
    const long arow = row0 + m;

    floatx4 acc[NT] = {};
    for (int kk = 0; kk < 128; kk += 32) {
        __syncthreads();                        // protect previous phase's reads
        for (int t = tid; t < COUT * 4; t += 256) {
            int c = t >> 2, ch = t & 3;
            *(half8*)&sWh[c][ch * 8] = *(const half8*)&Whi[(size_t)c * 128 + kk + ch * 8];
            *(half8*)&sWl[c][ch * 8] = *(const half8*)&Wlo[(size_t)c * 128 + kk + ch * 8];
        }
        __syncthreads();
        if (active) {
            half8 ah, al;
            if constexpr (IN_F32) {
                float4 a0 = *(const float4*)&Af[(size_t)arow * 128 + kk + q * 8];
                float4 a1 = *(const float4*)&Af[(size_t)arow * 128 + kk + q * 8 + 4];
                float av[8] = {a0.x, a0.y, a0.z, a0.w, a1.x, a1.y, a1.z, a1.w};
                #pragma unroll
                for (int x = 0; x < 8; ++x) {
                    ah[x] = (_Float16)av[x];
                    al[x] = (_Float16)(av[x] - (float)ah[x]);
                }
            } else {
                ah = *(const half8*)&Ahi[(size_t)arow * 128 + kk + q * 8];
                al = *(const half8*)&Alo[(size_t)arow * 128 + kk + q * 8];
            }
            #pragma unroll
            for (int nt = 0; nt < NT; ++nt) {
                half8 bh = *(const half8*)&sWh[nt * 16 + m][q * 8];
                half8 bl = *(const half8*)&sWl[nt * 16 + m][q * 8];
                acc[nt] = __builtin_amdgcn_mfma_f32_16x16x32_f16(ah, bh, acc[nt], 0, 0, 0);
                acc[nt] = __builtin_amdgcn_mfma_f32_16x16x32_f16(al, bh, acc[nt], 0, 0, 0);
                acc[nt] = __builtin_amdgcn_mfma_f32_16x16x32_f16(ah, bl, acc[nt], 0, 0, 0);
            }
        }
    }
    if (active) {
        // C/D layout: col = lane&15, row = (lane>>4)*4 + reg
        #pragma unroll
        for (int nt = 0; nt < NT; ++nt) {
            int col = nt * 16 + m;
            float b = (col < COUT / 2) ? B0[col] : B1[col - COUT / 2];
            #pragma unroll
            for (int r = 0; r < 4; ++r) {
                long grow = row0 + q * 4 + r;
                out[(size_t)grow * COUT + col] = (_Float16)(acc[nt][r] + b);
            }
        }
    }
}

// Fused: blocks [0,gB) run gemm1 (COUT=256, fp32 in); blocks [gB,..) run single-pass
// scatter. Scatter tail is short streaming work (not atomic-latency) -> compatible
// resource profile (vs R10's count_rank fusion, which was not).
__global__ __launch_bounds__(256) void k_gemm1_scatter(const float* __restrict__ x,
                                                       const _Float16* __restrict__ W1h,
                                                       const _Float16* __restrict__ W1lo,
                                                       const float* __restrict__ B0,
                                                       const float* __restrict__ B1,
                                                       _Float16* __restrict__ buf1, int n_rows,
                                                       const int* __restrict__ ei, int E,
                                                       const int* __restrict__ rowptr,
                                                       const int* __restrict__ rank,
                                                       int* __restrict__ adj, int gB) {
    __shared__ _Float16 sWh[256][40];
    __shared__ _Float16 sWl[256][40];
    const int bid = blockIdx.x, tid = threadIdx.x;
    if (bid < gB) {
        gemm_body<256, true>(bid, tid, sWh, sWl, x, nullptr, nullptr, n_rows,
                             W1h, W1lo, B0, B1, buf1);
    } else {
        int i = (bid - gB) * 256 + tid;
        int T = E + n_rows;
        if (i < T) {
            int dst = (i < E) ? ei[E + i] : (i - E);
            int src = (i < E) ? ei[i] : dst;
            adj[rowptr[dst] + rank[i]] = src;
        }
    }
}

template <int COUT, bool IN_F32>
__global__ __launch_bounds__(256) void gemm_mfma(const float* __restrict__ Af,
                                                 const _Float16* __restrict__ Ahi,
                                                 const _Float16* __restrict__ Alo, int n_rows,
                                                 const _Float16* __restrict__ Whi,
                                                 const _Float16* __restrict__ Wlo,
                                                 const float* __restrict__ B0,
                                                 const float* __restrict__ B1,
                                                 _Float16* __restrict__ out) {
    __shared__ _Float16 sWh[COUT][40];
    __shared__ _Float16 sWl[COUT][40];
    gemm_body<COUT, IN_F32>(blockIdx.x, threadIdx.x, sWh, sWl, Af, Ahi, Alo, n_rows,
                            Whi, Wlo, B0, B1, out);
}

// ---------------- fused GATv2 conv1 edge phase (heads=2, ch=64) ----------------
// R7-verbatim: inner loop R0 body, 128-thread blocks = 2 nodes/block. Do not touch.

__global__ __launch_bounds__(128) void conv1_fused(const _Float16* __restrict__ buf,
                                                   const int* __restrict__ rowptr,
                                                   const int* __restrict__ adj,
                                                   const float* __restrict__ att,   // [128]
                                                   const float* __restrict__ bias,  // [128]
                                                   _Float16* __restrict__ h1hi,
                                                   _Float16* __restrict__ h1lo, int n) {
    __shared__ _Float16 sxl[2][16][136];   // 272B row stride, 16B-aligned
    __shared__ _Float16 sxr[2][128];
    __shared__ float    sw[2][2][16];
    __shared__ _Float16 satt[128];
    const int tid = threadIdx.x, lane = tid & 63, wv = tid >> 6;
    satt[tid] = (_Float16)att[tid];        // 128 threads cover [128]
    __syncthreads();                        // all threads reach; no block barriers after this
    int node = blockIdx.x * 2 + wv;
    if (node >= n) return;

    const int jlane = lane & 15;           // edge slot within chunk
    const int grp = lane >> 4;             // channel quarter 0..3 (0,1->head0; 2,3->head1)
    const int chq = grp * 32;
    const int head = grp >> 1;
    const int wselg = lane >> 5;           // phase-B head for channels lane*2 (0..127)
    if (lane < 16)
        *(half8*)&sxr[wv][lane * 8] = *(const half8*)&buf[(size_t)node * 256 + 128 + lane * 8];
    asm volatile("s_waitcnt lgkmcnt(0)" ::: "memory");

    const int s = rowptr[node], e = rowptr[node + 1];
    float2 accA = {0.f, 0.f}, accB = {0.f, 0.f};
    float denA = 0.f, denB = 0.f;
    for (int c0 = s; c0 < e; c0 += 16) {
        const int cnt = min(16, e - c0);
        float sacc0 = 0.f, sacc1 = 0.f;
        if (jlane < cnt) {
            int src = adj[c0 + jlane];
            const _Float16* xlp = &buf[(size_t)src * 256 + chq];
            #pragma unroll
            for (int k = 0; k < 4; ++k) {
                half8 l = *(const half8*)&xlp[k * 8];
                half8 r = *(const half8*)&sxr[wv][chq + k * 8];
                half8 a = *(const half8*)&satt[chq + k * 8];
                *(half8*)&sxl[wv][jlane][chq + k * 8] = l;
                float* sp = (k & 1) ? &sacc1 : &sacc0;
                #pragma unroll
                for (int p = 0; p < 4; ++p) {
                    half2v lp = {l[2 * p], l[2 * p + 1]};
                    half2v rp = {r[2 * p], r[2 * p + 1]};
                    half2v ap = {a[2 * p], a[2 * p + 1]};
                    *sp = dot2(lrelu2(lp + rp), ap, *sp);
                }
            }
        }
        float sacc = sacc0 + sacc1;
        float efull = sacc + __shfl_xor(sacc, 16);   // combine the two quarters of this head
        if ((grp & 1) == 0 && jlane < cnt) sw[wv][head][jlane] = __expf(efull);
        asm volatile("s_waitcnt lgkmcnt(0)" ::: "memory");
        // phase B: lane -> channels (2*lane, 2*lane+1); its head's weights; 2-way unroll
        int j = 0;
        for (; j + 1 < cnt; j += 2) {
            float w0 = sw[wv][wselg][j], w1 = sw[wv][wselg][j + 1];
            half2v v0 = *(const half2v*)&sxl[wv][j][lane * 2];
            half2v v1 = *(const half2v*)&sxl[wv][j + 1][lane * 2];
            accA.x += w0 * (float)v0[0]; accA.y += w0 * (float)v0[1]; denA += w0;
            accB.x += w1 * (float)v1[0]; accB.y += w1 * (float)v1[1]; denB += w1;
        }
        if (j < cnt) {
            float w0 = sw[wv][wselg][j];
            half2v v0 = *(const half2v*)&sxl[wv][j][lane * 2];
            accA.x += w0 * (float)v0[0]; accA.y += w0 * (float)v0[1]; denA += w0;
        }
        asm volatile("s_waitcnt lgkmcnt(0)" ::: "memory");  // drain reads before next overwrite
    }
    float inv = 1.f / (denA + denB);
    float2 b = *(const float2*)&bias[lane * 2];
    float ox = lrelu((accA.x + accB.x) * inv + b.x, ACT_SLOPE);
    float oy = lrelu((accA.y + accB.y) * inv + b.y, ACT_SLOPE);
    half2v hv, lv;
    hv[0] = (_Float16)ox; lv[0] = (_Float16)(ox - (float)hv[0]);
    hv[1] = (_Float16)oy; lv[1] = (_Float16)(oy - (float)hv[1]);
    *(half2v*)&h1hi[(size_t)node * 128 + lane * 2] = hv;
    *(half2v*)&h1lo[(size_t)node * 128 + lane * 2] = lv;
}

// ---------------- fused GATv2 conv2 edge phase (heads=1, ch=64) ----------------
// R11-verbatim: chunk=32, 2 lanes/edge (one chunk round per typical node).
// Pool accumulation fused into epilogue (atomicAdd into gsum[G][64]).

__global__ __launch_bounds__(128) void conv2_fused(const _Float16* __restrict__ buf,
                                                   const int* __restrict__ rowptr,
                                                   const int* __restrict__ adj,
                                                   const float* __restrict__ att,    // [64]
                                                   const float* __restrict__ bias,   // [64]
                                                   const int* __restrict__ batch,    // [N]
                                                   float* __restrict__ gsum, int n) {
    __shared__ _Float16 sxl[2][32][72];    // 144B row stride, 16B-aligned
    __shared__ _Float16 sxr[2][64];
    __shared__ float    sw[2][32];
    __shared__ _Float16 satt[64];
    const int tid = threadIdx.x, lane = tid & 63, wv = tid >> 6;
    if (tid < 64) satt[tid] = (_Float16)att[tid];
    __syncthreads();
    int node = blockIdx.x * 2 + wv;
    if (node >= n) return;

    const int j = lane & 31;               // edge slot within chunk
    const int g = lane >> 5;               // channel half (32 ch each)
    const int ch0 = g * 32;
    if (lane < 8)
        *(half8*)&sxr[wv][lane * 8] = *(const half8*)&buf[(size_t)node * 128 + 64 + lane * 8];
    asm volatile("s_waitcnt lgkmcnt(0)" ::: "memory");

    const int s = rowptr[node], e = rowptr[node + 1];
    float accA = 0.f, accB = 0.f, denA = 0.f, denB = 0.f;
    for (int c0 = s; c0 < e; c0 += 32) {
        const int cnt = min(32, e - c0);
        float sacc = 0.f;
        if (j < cnt) {
            int src = adj[c0 + j];
            const _Float16* xlp = &buf[(size_t)src * 128 + ch0];
            #pragma unroll
            for (int k = 0; k < 4; ++k) {
                half8 l = *(const half8*)&xlp[k * 8];
                half8 r = *(const half8*)&sxr[wv][ch0 + k * 8];
                half8 a = *(const half8*)&satt[ch0 + k * 8];
                *(half8*)&sxl[wv][j][ch0 + k * 8] = l;
                #pragma unroll
                for (int p = 0; p < 4; ++p) {
                    half2v lp = {l[2 * p], l[2 * p + 1]};
                    half2v rp = {r[2 * p], r[2 * p + 1]};
                    half2v ap = {a[2 * p], a[2 * p + 1]};
                    sacc = dot2(lrelu2(lp + rp), ap, sacc);
                }
            }
        }
        float efull = sacc + __shfl_xor(sacc, 32);   // combine the two channel halves
        if (g == 0 && j < cnt) sw[wv][j] = __expf(efull);
        asm volatile("s_waitcnt lgkmcnt(0)" ::: "memory");
        // phase B: lane -> channel lane; 2-way unroll over up to 32 edges
        int jj = 0;
        for (; jj + 1 < cnt; jj += 2) {
            float w0 = sw[wv][jj], w1 = sw[wv][jj + 1];
            accA += w0 * (float)sxl[wv][jj][lane];     denA += w0;
            accB += w1 * (float)sxl[wv][jj + 1][lane]; denB += w1;
        }
        if (jj < cnt) {
            float w0 = sw[wv][jj];
            accA += w0 * (float)sxl[wv][jj][lane];
            denA += w0;
        }
        asm volatile("s_waitcnt lgkmcnt(0)" ::: "memory");
    }
    float val = lrelu((accA + accB) / (denA + denB) + bias[lane], ACT_SLOPE);
    atomicAdd(&gsum[(size_t)batch[node] * 64 + lane], val);
}

// ---------------- pooled MLP head: gsum/cnt -> fc1 -> lrelu -> fc2 ----------------

__device__ __forceinline__ int lower_bound(const int* a, int n, int v) {
    int lo = 0, hi = n;
    while (lo < hi) { int mid = (lo + hi) >> 1; if (a[mid] < v) lo = mid + 1; else hi = mid; }
    return lo;
}

__global__ __launch_bounds__(256) void pool_mlp(const float* __restrict__ gsum,  // [G,64]
                                                const int* __restrict__ batch,   // [N] sorted
                                                const float* __restrict__ fc1_w,
                                                const float* __restrict__ fc1_b,
                                                const float* __restrict__ fc2_w,
                                                const float* __restrict__ fc2_b,
                                                float* __restrict__ out, int n) {
    const int g = blockIdx.x;
    const int tid = threadIdx.x;
    __shared__ float pooled[64];
    __shared__ float hmid[64];

    int lo = lower_bound(batch, n, g);
    int hi = lower_bound(batch, n, g + 1);
    float inv = 1.f / (float)max(hi - lo, 1);

    if (tid < 64) pooled[tid] = gsum[(size_t)g * 64 + tid] * inv;
    __syncthreads();
    if (tid < 64) {
        float acc = fc1_b[tid];
        const float* w = &fc1_w[(size_t)tid * 64];
        #pragma unroll
        for (int k = 0; k < 64; ++k) acc += pooled[k] * w[k];
        hmid[tid] = lrelu(acc, ACT_SLOPE);
    }
    __syncthreads();
    for (int o = tid; o < 768; o += 256) {
        float acc = fc2_b[o];
        const float* w = &fc2_w[(size_t)o * 64];
        #pragma unroll
        for (int k = 0; k < 64; ++k) acc += hmid[k] * w[k];
        out[(size_t)g * 768 + o] = acc;
    }
}

// ---------------- launch ----------------

extern "C" void kernel_launch(void* const* d_in, const int* in_sizes, int n_in,
                              void* d_out, int out_size, void* d_ws, size_t ws_size,
                              hipStream_t stream) {
    const float* x     = (const float*)d_in[0];
    const int*   ei    = (const int*)d_in[1];
    const int*   batch = (const int*)d_in[2];
    const float* w1_l  = (const float*)d_in[3];
    const float* b1_l  = (const float*)d_in[4];
    const float* w1_r  = (const float*)d_in[5];
    const float* b1_r  = (const float*)d_in[6];
    const float* att1  = (const float*)d_in[7];
    const float* bias1 = (const float*)d_in[8];
    const float* w2_l  = (const float*)d_in[9];
    const float* b2_l  = (const float*)d_in[10];
    const float* w2_r  = (const float*)d_in[11];
    const float* b2_r  = (const float*)d_in[12];
    const float* att2  = (const float*)d_in[13];
    const float* bias2 = (const float*)d_in[14];
    const float* fc1_w = (const float*)d_in[15];
    const float* fc1_b = (const float*)d_in[16];
    const float* fc2_w = (const float*)d_in[17];
    const float* fc2_b = (const float*)d_in[18];
    float* out = (float*)d_out;

    const int N = in_sizes[2];
    const int E = in_sizes[1] / 2;
    const int T = E + N;
    const int G = out_size / 768;

    char* ws = (char*)d_ws;
    size_t off = 0;
    auto alloc = [&](size_t bytes) -> void* {
        void* p = ws + off;
        off = (off + bytes + 255) & ~(size_t)255;
        return p;
    };
    int*      deg    = (int*)alloc((size_t)N * 4);
    int*      rowptr = (int*)alloc((size_t)(N + 1) * 4);
    int*      rank   = (int*)alloc((size_t)T * 4);
    int*      bsum   = (int*)alloc(1024);
    int*      adj    = (int*)alloc((size_t)T * 4);
    _Float16* h1hi   = (_Float16*)alloc((size_t)N * 128 * 2);
    _Float16* h1lo   = (_Float16*)alloc((size_t)N * 128 * 2);
    _Float16* W1h    = (_Float16*)alloc(32768 * 2);
    _Float16* W1lo   = (_Float16*)alloc(32768 * 2);
    _Float16* W2h    = (_Float16*)alloc(16384 * 2);
    _Float16* W2lo   = (_Float16*)alloc(16384 * 2);
    float*    gsum   = (float*)alloc((size_t)G * 64 * 4);
    _Float16* buf1   = (_Float16*)alloc((size_t)N * 256 * 2);
    // lifetime aliasing: buf1 (N*512 B) dead after conv1_fused -> buf2 fp16 [N,128]
    // (N*256 B) reuses the first half.
    _Float16* buf2 = buf1;

    const int nbN  = (N + 255) / 256;           // <= 256 required by k_scan_add (N <= 65536)
    const int nbT  = (T + 255) / 256;
    const int mfmG = (N / 16 + 3) / 4;          // 16-row tiles, 4 per 256-thread block
    const int edgG = (N + 1) / 2;               // 2 nodes per 128-thread block
    const int encG = (49152 + G * 64 + N + 255) / 256;

    // ---- weight encode + gsum zero + deg zero (independent; runs first) ----
    k_encode_w<<<encG, 256, 0, stream>>>(w1_l, w1_r, w2_l, w2_r,
                                         W1h, W1lo, W2h, W2lo, gsum, G * 64, deg, N);

    // ---- CSR build ----
    k_count_rank<<<nbT, 256, 0, stream>>>(ei, E, N, deg, rank);
    k_scan_block<<<nbN, 256, 0, stream>>>(deg, N, rowptr + 1, bsum);
    k_scan_add<<<nbN, 256, 0, stream>>>(rowptr, bsum, N);

    // ---- gemm1 (blocks [0,mfmG)) fused with single-pass scatter (blocks [mfmG,..)) ----
    k_gemm1_scatter<<<mfmG + nbT, 256, 0, stream>>>(x, W1h, W1lo, b1_l, b1_r, buf1, N,
                                                    ei, E, rowptr, rank, adj, mfmG);

    // ---- conv1 ----
    conv1_fused<<<edgG, 128, 0, stream>>>(buf1, rowptr, adj, att1, bias1, h1hi, h1lo, N);

    // ---- conv2 (pool accumulation fused into epilogue) ----
    gemm_mfma<128, false><<<mfmG, 256, 0, stream>>>(nullptr, h1hi, h1lo, N,
                                                    W2h, W2lo, b2_l, b2_r, buf2);
    conv2_fused<<<edgG, 128, 0, stream>>>(buf2, rowptr, adj, att2, bias2, batch, gsum, N);

    // ---- MLP head ----
    pool_mlp<<<G, 256, 0, stream>>>(gsum, batch, fc1_w, fc1_b, fc2_w, fc2_b, out, N);
}

// Round 14
// 290.423 us; speedup vs baseline: 1.2242x; 1.0456x over previous
//
#include <hip/hip_runtime.h>

#define ATT_SLOPE 0.2f
#define ACT_SLOPE 0.01f

typedef _Float16 half8  __attribute__((ext_vector_type(8)));
typedef _Float16 half2v __attribute__((ext_vector_type(2)));
typedef float    floatx4 __attribute__((ext_vector_type(4)));

#if defined(__has_builtin)
#if __has_builtin(__builtin_amdgcn_fdot2)
#define HAVE_FDOT2 1
#endif
#endif

__device__ __forceinline__ float lrelu(float v, float s) {
    return fmaxf(v, v * s);
}

__device__ __forceinline__ half2v lrelu2(half2v m) {
    half2v t = m * (_Float16)ATT_SLOPE;
    return __builtin_elementwise_max(m, t);
}

__device__ __forceinline__ float dot2(half2v a, half2v b, float c) {
#ifdef HAVE_FDOT2
    return __builtin_amdgcn_fdot2(a, b, c, false);
#else
    return c + (float)a[0] * (float)b[0] + (float)a[1] * (float)b[1];
#endif
}

// ---------------- CSR build (edges grouped by dst, self loops appended) ----------------

// count + stable rank within dst. Standalone (no LDS) at max occupancy (R10 lesson).
__global__ __launch_bounds__(256) void k_count_rank(const int* __restrict__ ei, int E, int N,
                                                    int* __restrict__ deg,
                                                    int* __restrict__ rank) {
    int i = blockIdx.x * 256 + threadIdx.x;
    int total = E + N;
    if (i >= total) return;
    int dst = (i < E) ? ei[E + i] : (i - E);
    rank[i] = atomicAdd(&deg[dst], 1);
}

// per-node prefix-scan of deg + degree histogram (LDS two-level) for the counting sort.
__global__ __launch_bounds__(256) void k_scan_block(const int* __restrict__ deg, int n,
                                                    int* __restrict__ rp1, int* __restrict__ bsum,
                                                    int* __restrict__ hist) {
    __shared__ int s[256];
    __shared__ int lh[64];
    int tid = threadIdx.x;
    int i = blockIdx.x * 256 + tid;
    int dv = (i < n) ? deg[i] : 0;
    s[tid] = dv;
    if (tid < 64) lh[tid] = 0;
    __syncthreads();
    if (i < n) atomicAdd(&lh[min(dv, 63)], 1);
    for (int off = 1; off < 256; off <<= 1) {
        int t = (tid >= off) ? s[tid - off] : 0;
        __syncthreads();
        s[tid] += t;
        __syncthreads();
    }
    if (i < n) rp1[i] = s[tid];
    if (tid == 255) bsum[blockIdx.x] = s[255];
    if (tid < 64 && lh[tid]) atomicAdd(&hist[tid], lh[tid]);
}

// merged bsum-scan + add: each block redundantly reduces bsum[0..blockIdx) in LDS
// (nbN <= 256 guaranteed for N <= 65536).
__global__ __launch_bounds__(256) void k_scan_add(int* __restrict__ rowptr,
                                                  const int* __restrict__ bsum, int n) {
    __shared__ int s[256];
    int tid = threadIdx.x, bid = blockIdx.x;
    s[tid] = (tid < bid) ? bsum[tid] : 0;
    __syncthreads();
    for (int off = 128; off > 0; off >>= 1) {
        if (tid < off) s[tid] += s[tid + off];
        __syncthreads();
    }
    int boff = s[0];
    int i = bid * 256 + tid;
    if (i < n) rowptr[i + 1] += boff;
    if (i == 0) rowptr[0] = 0;
}

// counting-sort permutation, DESCENDING degree: equal-degree nodes pair up in conv
// blocks (no intra-block convoy) and the biggest nodes launch first (no drain tail).
// Two-level cursor reservation: LDS count per bucket, ONE global atomic per bucket/block.
__global__ __launch_bounds__(256) void k_perm(const int* __restrict__ deg, int n,
                                              const int* __restrict__ hist,
                                              int* __restrict__ cursor,
                                              int* __restrict__ perm) {
    __shared__ int lh[64], gb[64], bb[64];
    int tid = threadIdx.x, i = blockIdx.x * 256 + tid;
    if (tid < 64) lh[tid] = 0;
    __syncthreads();
    int b = 0, lpos = 0;
    if (i < n) { b = min(deg[i], 63); lpos = atomicAdd(&lh[b], 1); }
    __syncthreads();
    if (tid < 64) {
        gb[tid] = lh[tid] ? atomicAdd(&cursor[tid], lh[tid]) : 0;
        int s = 0;
        for (int k = 63; k > tid; --k) s += hist[k];   // descending bucket layout
        bb[tid] = s;
    }
    __syncthreads();
    if (i < n) perm[bb[b] + gb[b] + lpos] = i;
}

// -- weight hi/lo fp16 split encode + gsum/deg/hist/cursor zero (one launch, runs FIRST) --

__global__ __launch_bounds__(256) void k_encode_w(const float* __restrict__ w1l,
                                                  const float* __restrict__ w1r,
                                                  const float* __restrict__ w2l,
                                                  const float* __restrict__ w2r,
                                                  _Float16* __restrict__ W1h,
                                                  _Float16* __restrict__ W1lo,
                                                  _Float16* __restrict__ W2h,
                                                  _Float16* __restrict__ W2lo,
                                                  float* __restrict__ gsum, int gn,
                                                  int* __restrict__ deg, int n,
                                                  int* __restrict__ hc) {  // hist[64]+cursor[64]
    int i = blockIdx.x * 256 + threadIdx.x;   // 0 .. 49151 + gn + n + 128
    if (i >= 49152 + gn + n + 128) return;
    if (i >= 49152 + gn + n) {                 // zero hist+cursor
        hc[i - 49152 - gn - n] = 0;
        return;
    }
    if (i >= 49152 + gn) {                     // zero deg (replaces hipMemsetAsync launch)
        deg[i - 49152 - gn] = 0;
        return;
    }
    if (i >= 49152) {                          // zero the pool accumulator each launch
        gsum[i - 49152] = 0.f;
        return;
    }
    float v;
    _Float16 *ph, *pl;
    int idx;
    if (i < 32768) {
        idx = i;
        v = (i < 16384) ? w1l[i] : w1r[i - 16384];
        ph = W1h; pl = W1lo;
    } else {
        int j = i - 32768;
        idx = j;
        v = (j < 8192) ? w2l[j] : w2r[j - 8192];
        ph = W2h; pl = W2lo;
    }
    _Float16 h = (_Float16)v;
    ph[idx] = h;
    pl[idx] = (_Float16)(v - (float)h);
}

// ------------- MFMA split-f16 dual linear, 256-thread blocks (4 waves, 64 rows) -------------
// LDS-staged W (R12 proved direct-from-global W costs 76-81us: per-lane VMEM issue +
// VGPR 80 + 25% occupancy; staging reads W once per block and serves fragments from LDS).

template <int COUT, bool IN_F32>
__device__ __forceinline__ void gemm_body(int bid, int tid,
                                          _Float16 (*sWh)[40], _Float16 (*sWl)[40],
                                          const float* __restrict__ Af,
                                          const _Float16* __restrict__ Ahi,
                                          const _Float16* __restrict__ Alo, int n_rows,
                                          const _Float16* __restrict__ Whi,
                                          const _Float16* __restrict__ Wlo,
                                          const float* __restrict__ B0,
                                          const float* __restrict__ B1,
                                          _Float16* __restrict__ out) {
    constexpr int NT = COUT / 16;
    const int lane = tid & 63, wv = tid >> 6;   // wv in [0,4)
    const int m = lane & 15, q = lane >> 4;
    const long row0 = ((long)bid * 4 + wv) * 16;
    const bool active = row0 < n_rows;          // wave-uniform (n_rows % 16 == 0)
    const long arow = row0 + m;

    floatx4 acc[NT] = {};
    for (int kk = 0; kk < 128; kk += 32) {
        __syncthreads();                        // protect previous phase's reads
        for (int t = tid; t < COUT * 4; t += 256) {
            int c = t >> 2, ch = t & 3;
            *(half8*)&sWh[c][ch * 8] = *(const half8*)&Whi[(size_t)c * 128 + kk + ch * 8];
            *(half8*)&sWl[c][ch * 8] = *(const half8*)&Wlo[(size_t)c * 128 + kk + ch * 8];
        }
        __syncthreads();
        if (active) {
            half8 ah, al;
            if constexpr (IN_F32) {
                float4 a0 = *(const float4*)&Af[(size_t)arow * 128 + kk + q * 8];
                float4 a1 = *(const float4*)&Af[(size_t)arow * 128 + kk + q * 8 + 4];
                float av[8] = {a0.x, a0.y, a0.z, a0.w, a1.x, a1.y, a1.z, a1.w};
                #pragma unroll
                for (int x = 0; x < 8; ++x) {
                    ah[x] = (_Float16)av[x];
                    al[x] = (_Float16)(av[x] - (float)ah[x]);
                }
            } else {
                ah = *(const half8*)&Ahi[(size_t)arow * 128 + kk + q * 8];
                al = *(const half8*)&Alo[(size_t)arow * 128 + kk + q * 8];
            }
            #pragma unroll
            for (int nt = 0; nt < NT; ++nt) {
                half8 bh = *(const half8*)&sWh[nt * 16 + m][q * 8];
                half8 bl = *(const half8*)&sWl[nt * 16 + m][q * 8];
                acc[nt] = __builtin_amdgcn_mfma_f32_16x16x32_f16(ah, bh, acc[nt], 0, 0, 0);
                acc[nt] = __builtin_amdgcn_mfma_f32_16x16x32_f16(al, bh, acc[nt], 0, 0, 0);
                acc[nt] = __builtin_amdgcn_mfma_f32_16x16x32_f16(ah, bl, acc[nt], 0, 0, 0);
            }
        }
    }
    if (active) {
        // C/D layout: col = lane&15, row = (lane>>4)*4 + reg
        #pragma unroll
        for (int nt = 0; nt < NT; ++nt) {
            int col = nt * 16 + m;
            float b = (col < COUT / 2) ? B0[col] : B1[col - COUT / 2];
            #pragma unroll
            for (int r = 0; r < 4; ++r) {
                long grow = row0 + q * 4 + r;
                out[(size_t)grow * COUT + col] = (_Float16)(acc[nt][r] + b);
            }
        }
    }
}

// Fused: blocks [0,gB) run gemm1 (COUT=256, fp32 in); blocks [gB,..) run single-pass
// scatter (streaming, occupancy-insensitive -> compatible with the 40KB-LDS gemm half).
__global__ __launch_bounds__(256) void k_gemm1_scatter(const float* __restrict__ x,
                                                       const _Float16* __restrict__ W1h,
                                                       const _Float16* __restrict__ W1lo,
                                                       const float* __restrict__ B0,
                                                       const float* __restrict__ B1,
                                                       _Float16* __restrict__ buf1, int n_rows,
                                                       const int* __restrict__ ei, int E,
                                                       const int* __restrict__ rowptr,
                                                       const int* __restrict__ rank,
                                                       int* __restrict__ adj, int gB) {
    __shared__ _Float16 sWh[256][40];
    __shared__ _Float16 sWl[256][40];
    const int bid = blockIdx.x, tid = threadIdx.x;
    if (bid < gB) {
        gemm_body<256, true>(bid, tid, sWh, sWl, x, nullptr, nullptr, n_rows,
                             W1h, W1lo, B0, B1, buf1);
    } else {
        int i = (bid - gB) * 256 + tid;
        int T = E + n_rows;
        if (i < T) {
            int dst = (i < E) ? ei[E + i] : (i - E);
            int src = (i < E) ? ei[i] : dst;
            adj[rowptr[dst] + rank[i]] = src;
        }
    }
}

template <int COUT, bool IN_F32>
__global__ __launch_bounds__(256) void gemm_mfma(const float* __restrict__ Af,
                                                 const _Float16* __restrict__ Ahi,
                                                 const _Float16* __restrict__ Alo, int n_rows,
                                                 const _Float16* __restrict__ Whi,
                                                 const _Float16* __restrict__ Wlo,
                                                 const float* __restrict__ B0,
                                                 const float* __restrict__ B1,
                                                 _Float16* __restrict__ out) {
    __shared__ _Float16 sWh[COUT][40];
    __shared__ _Float16 sWl[COUT][40];
    gemm_body<COUT, IN_F32>(blockIdx.x, threadIdx.x, sWh, sWl, Af, Ahi, Alo, n_rows,
                            Whi, Wlo, B0, B1, out);
}

// ---------------- fused GATv2 conv1 edge phase (heads=2, ch=64) ----------------
// Inner loop R0-verbatim; 128-thread blocks = 2 nodes/block. ONLY change vs R11:
// node = perm[idx] (degree-sorted, descending) — prologue-only, hot loop untouched.

__global__ __launch_bounds__(128) void conv1_fused(const _Float16* __restrict__ buf,
                                                   const int* __restrict__ rowptr,
                                                   const int* __restrict__ adj,
                                                   const int* __restrict__ perm,
                                                   const float* __restrict__ att,   // [128]
                                                   const float* __restrict__ bias,  // [128]
                                                   _Float16* __restrict__ h1hi,
                                                   _Float16* __restrict__ h1lo, int n) {
    __shared__ _Float16 sxl[2][16][136];   // 272B row stride, 16B-aligned
    __shared__ _Float16 sxr[2][128];
    __shared__ float    sw[2][2][16];
    __shared__ _Float16 satt[128];
    const int tid = threadIdx.x, lane = tid & 63, wv = tid >> 6;
    satt[tid] = (_Float16)att[tid];        // 128 threads cover [128]
    __syncthreads();                        // all threads reach; no block barriers after this
    int idx = blockIdx.x * 2 + wv;
    if (idx >= n) return;
    int node = perm[idx];                   // degree-paired, biggest-first

    const int jlane = lane & 15;           // edge slot within chunk
    const int grp = lane >> 4;             // channel quarter 0..3 (0,1->head0; 2,3->head1)
    const int chq = grp * 32;
    const int head = grp >> 1;
    const int wselg = lane >> 5;           // phase-B head for channels lane*2 (0..127)
    if (lane < 16)
        *(half8*)&sxr[wv][lane * 8] = *(const half8*)&buf[(size_t)node * 256 + 128 + lane * 8];
    asm volatile("s_waitcnt lgkmcnt(0)" ::: "memory");

    const int s = rowptr[node], e = rowptr[node + 1];
    float2 accA = {0.f, 0.f}, accB = {0.f, 0.f};
    float denA = 0.f, denB = 0.f;
    for (int c0 = s; c0 < e; c0 += 16) {
        const int cnt = min(16, e - c0);
        float sacc0 = 0.f, sacc1 = 0.f;
        if (jlane < cnt) {
            int src = adj[c0 + jlane];
            const _Float16* xlp = &buf[(size_t)src * 256 + chq];
            #pragma unroll
            for (int k = 0; k < 4; ++k) {
                half8 l = *(const half8*)&xlp[k * 8];
                half8 r = *(const half8*)&sxr[wv][chq + k * 8];
                half8 a = *(const half8*)&satt[chq + k * 8];
                *(half8*)&sxl[wv][jlane][chq + k * 8] = l;
                float* sp = (k & 1) ? &sacc1 : &sacc0;
                #pragma unroll
                for (int p = 0; p < 4; ++p) {
                    half2v lp = {l[2 * p], l[2 * p + 1]};
                    half2v rp = {r[2 * p], r[2 * p + 1]};
                    half2v ap = {a[2 * p], a[2 * p + 1]};
                    *sp = dot2(lrelu2(lp + rp), ap, *sp);
                }
            }
        }
        float sacc = sacc0 + sacc1;
        float efull = sacc + __shfl_xor(sacc, 16);   // combine the two quarters of this head
        if ((grp & 1) == 0 && jlane < cnt) sw[wv][head][jlane] = __expf(efull);
        asm volatile("s_waitcnt lgkmcnt(0)" ::: "memory");
        // phase B: lane -> channels (2*lane, 2*lane+1); its head's weights; 2-way unroll
        int j = 0;
        for (; j + 1 < cnt; j += 2) {
            float w0 = sw[wv][wselg][j], w1 = sw[wv][wselg][j + 1];
            half2v v0 = *(const half2v*)&sxl[wv][j][lane * 2];
            half2v v1 = *(const half2v*)&sxl[wv][j + 1][lane * 2];
            accA.x += w0 * (float)v0[0]; accA.y += w0 * (float)v0[1]; denA += w0;
            accB.x += w1 * (float)v1[0]; accB.y += w1 * (float)v1[1]; denB += w1;
        }
        if (j < cnt) {
            float w0 = sw[wv][wselg][j];
            half2v v0 = *(const half2v*)&sxl[wv][j][lane * 2];
            accA.x += w0 * (float)v0[0]; accA.y += w0 * (float)v0[1]; denA += w0;
        }
        asm volatile("s_waitcnt lgkmcnt(0)" ::: "memory");  // drain reads before next overwrite
    }
    float inv = 1.f / (denA + denB);
    float2 b = *(const float2*)&bias[lane * 2];
    float ox = lrelu((accA.x + accB.x) * inv + b.x, ACT_SLOPE);
    float oy = lrelu((accA.y + accB.y) * inv + b.y, ACT_SLOPE);
    half2v hv, lv;
    hv[0] = (_Float16)ox; lv[0] = (_Float16)(ox - (float)hv[0]);
    hv[1] = (_Float16)oy; lv[1] = (_Float16)(oy - (float)hv[1]);
    *(half2v*)&h1hi[(size_t)node * 128 + lane * 2] = hv;
    *(half2v*)&h1lo[(size_t)node * 128 + lane * 2] = lv;
}

// ---------------- fused GATv2 conv2 edge phase (heads=1, ch=64) ----------------
// R11-verbatim body (chunk=32, 2 lanes/edge); ONLY change: node = perm[idx].
// Pool accumulation fused into epilogue (atomicAdd into gsum[G][64]).

__global__ __launch_bounds__(128) void conv2_fused(const _Float16* __restrict__ buf,
                                                   const int* __restrict__ rowptr,
                                                   const int* __restrict__ adj,
                                                   const int* __restrict__ perm,
                                                   const float* __restrict__ att,    // [64]
                                                   const float* __restrict__ bias,   // [64]
                                                   const int* __restrict__ batch,    // [N]
                                                   float* __restrict__ gsum, int n) {
    __shared__ _Float16 sxl[2][32][72];    // 144B row stride, 16B-aligned
    __shared__ _Float16 sxr[2][64];
    __shared__ float    sw[2][32];
    __shared__ _Float16 satt[64];
    const int tid = threadIdx.x, lane = tid & 63, wv = tid >> 6;
    if (tid < 64) satt[tid] = (_Float16)att[tid];
    __syncthreads();
    int idx = blockIdx.x * 2 + wv;
    if (idx >= n) return;
    int node = perm[idx];

    const int j = lane & 31;               // edge slot within chunk
    const int g = lane >> 5;               // channel half (32 ch each)
    const int ch0 = g * 32;
    if (lane < 8)
        *(half8*)&sxr[wv][lane * 8] = *(const half8*)&buf[(size_t)node * 128 + 64 + lane * 8];
    asm volatile("s_waitcnt lgkmcnt(0)" ::: "memory");

    const int s = rowptr[node], e = rowptr[node + 1];
    float accA = 0.f, accB = 0.f, denA = 0.f, denB = 0.f;
    for (int c0 = s; c0 < e; c0 += 32) {
        const int cnt = min(32, e - c0);
        float sacc = 0.f;
        if (j < cnt) {
            int src = adj[c0 + j];
            const _Float16* xlp = &buf[(size_t)src * 128 + ch0];
            #pragma unroll
            for (int k = 0; k < 4; ++k) {
                half8 l = *(const half8*)&xlp[k * 8];
                half8 r = *(const half8*)&sxr[wv][ch0 + k * 8];
                half8 a = *(const half8*)&satt[ch0 + k * 8];
                *(half8*)&sxl[wv][j][ch0 + k * 8] = l;
                #pragma unroll
                for (int p = 0; p < 4; ++p) {
                    half2v lp = {l[2 * p], l[2 * p + 1]};
                    half2v rp = {r[2 * p], r[2 * p + 1]};
                    half2v ap = {a[2 * p], a[2 * p + 1]};
                    sacc = dot2(lrelu2(lp + rp), ap, sacc);
                }
            }
        }
        float efull = sacc + __shfl_xor(sacc, 32);   // combine the two channel halves
        if (g == 0 && j < cnt) sw[wv][j] = __expf(efull);
        asm volatile("s_waitcnt lgkmcnt(0)" ::: "memory");
        // phase B: lane -> channel lane; 2-way unroll over up to 32 edges
        int jj = 0;
        for (; jj + 1 < cnt; jj += 2) {
            float w0 = sw[wv][jj], w1 = sw[wv][jj + 1];
            accA += w0 * (float)sxl[wv][jj][lane];     denA += w0;
            accB += w1 * (float)sxl[wv][jj + 1][lane]; denB += w1;
        }
        if (jj < cnt) {
            float w0 = sw[wv][jj];
            accA += w0 * (float)sxl[wv][jj][lane];
            denA += w0;
        }
        asm volatile("s_waitcnt lgkmcnt(0)" ::: "memory");
    }
    float val = lrelu((accA + accB) / (denA + denB) + bias[lane], ACT_SLOPE);
    atomicAdd(&gsum[(size_t)batch[node] * 64 + lane], val);
}

// ---------------- pooled MLP head: gsum/cnt -> fc1 -> lrelu -> fc2 ----------------

__device__ __forceinline__ int lower_bound(const int* a, int n, int v) {
    int lo = 0, hi = n;
    while (lo < hi) { int mid = (lo + hi) >> 1; if (a[mid] < v) lo = mid + 1; else hi = mid; }
    return lo;
}

__global__ __launch_bounds__(256) void pool_mlp(const float* __restrict__ gsum,  // [G,64]
                                                const int* __restrict__ batch,   // [N] sorted
                                                const float* __restrict__ fc1_w,
                                                const float* __restrict__ fc1_b,
                                                const float* __restrict__ fc2_w,
                                                const float* __restrict__ fc2_b,
                                                float* __restrict__ out, int n) {
    const int g = blockIdx.x;
    const int tid = threadIdx.x;
    __shared__ float pooled[64];
    __shared__ float hmid[64];

    int lo = lower_bound(batch, n, g);
    int hi = lower_bound(batch, n, g + 1);
    float inv = 1.f / (float)max(hi - lo, 1);

    if (tid < 64) pooled[tid] = gsum[(size_t)g * 64 + tid] * inv;
    __syncthreads();
    if (tid < 64) {
        float acc = fc1_b[tid];
        const float* w = &fc1_w[(size_t)tid * 64];
        #pragma unroll
        for (int k = 0; k < 64; ++k) acc += pooled[k] * w[k];
        hmid[tid] = lrelu(acc, ACT_SLOPE);
    }
    __syncthreads();
    for (int o = tid; o < 768; o += 256) {
        float acc = fc2_b[o];
        const float* w = &fc2_w[(size_t)o * 64];
        #pragma unroll
        for (int k = 0; k < 64; ++k) acc += hmid[k] * w[k];
        out[(size_t)g * 768 + o] = acc;
    }
}

// ---------------- launch ----------------

extern "C" void kernel_launch(void* const* d_in, const int* in_sizes, int n_in,
                              void* d_out, int out_size, void* d_ws, size_t ws_size,
                              hipStream_t stream) {
    const float* x     = (const float*)d_in[0];
    const int*   ei    = (const int*)d_in[1];
    const int*   batch = (const int*)d_in[2];
    const float* w1_l  = (const float*)d_in[3];
    const float* b1_l  = (const float*)d_in[4];
    const float* w1_r  = (const float*)d_in[5];
    const float* b1_r  = (const float*)d_in[6];
    const float* att1  = (const float*)d_in[7];
    const float* bias1 = (const float*)d_in[8];
    const float* w2_l  = (const float*)d_in[9];
    const float* b2_l  = (const float*)d_in[10];
    const float* w2_r  = (const float*)d_in[11];
    const float* b2_r  = (const float*)d_in[12];
    const float* att2  = (const float*)d_in[13];
    const float* bias2 = (const float*)d_in[14];
    const float* fc1_w = (const float*)d_in[15];
    const float* fc1_b = (const float*)d_in[16];
    const float* fc2_w = (const float*)d_in[17];
    const float* fc2_b = (const float*)d_in[18];
    float* out = (float*)d_out;

    const int N = in_sizes[2];
    const int E = in_sizes[1] / 2;
    const int T = E + N;
    const int G = out_size / 768;

    char* ws = (char*)d_ws;
    size_t off = 0;
    auto alloc = [&](size_t bytes) -> void* {
        void* p = ws + off;
        off = (off + bytes + 255) & ~(size_t)255;
        return p;
    };
    int*      deg    = (int*)alloc((size_t)N * 4);
    int*      rowptr = (int*)alloc((size_t)(N + 1) * 4);
    int*      rank   = (int*)alloc((size_t)T * 4);
    int*      bsum   = (int*)alloc(1024);
    int*      hc     = (int*)alloc(128 * 4);          // hist[64] + cursor[64]
    int*      perm   = (int*)alloc((size_t)N * 4);
    int*      adj    = (int*)alloc((size_t)T * 4);
    _Float16* h1hi   = (_Float16*)alloc((size_t)N * 128 * 2);
    _Float16* h1lo   = (_Float16*)alloc((size_t)N * 128 * 2);
    _Float16* W1h    = (_Float16*)alloc(32768 * 2);
    _Float16* W1lo   = (_Float16*)alloc(32768 * 2);
    _Float16* W2h    = (_Float16*)alloc(16384 * 2);
    _Float16* W2lo   = (_Float16*)alloc(16384 * 2);
    float*    gsum   = (float*)alloc((size_t)G * 64 * 4);
    _Float16* buf1   = (_Float16*)alloc((size_t)N * 256 * 2);
    // lifetime aliasing: buf1 (N*512 B) dead after conv1_fused -> buf2 fp16 [N,128]
    // (N*256 B) reuses the first half.
    _Float16* buf2 = buf1;
    int* hist   = hc;
    int* cursor = hc + 64;

    const int nbN  = (N + 255) / 256;           // <= 256 required by k_scan_add (N <= 65536)
    const int nbT  = (T + 255) / 256;
    const int mfmG = (N / 16 + 3) / 4;          // 16-row tiles, 4 per 256-thread block
    const int edgG = (N + 1) / 2;               // 2 nodes per 128-thread block
    const int encG = (49152 + G * 64 + N + 128 + 255) / 256;

    // ---- weight encode + gsum/deg/hist/cursor zero (independent; runs first) ----
    k_encode_w<<<encG, 256, 0, stream>>>(w1_l, w1_r, w2_l, w2_r,
                                         W1h, W1lo, W2h, W2lo, gsum, G * 64, deg, N, hc);

    // ---- CSR build + degree sort ----
    k_count_rank<<<nbT, 256, 0, stream>>>(ei, E, N, deg, rank);
    k_scan_block<<<nbN, 256, 0, stream>>>(deg, N, rowptr + 1, bsum, hist);
    k_scan_add<<<nbN, 256, 0, stream>>>(rowptr, bsum, N);
    k_perm<<<nbN, 256, 0, stream>>>(deg, N, hist, cursor, perm);

    // ---- gemm1 (blocks [0,mfmG)) fused with single-pass scatter (blocks [mfmG,..)) ----
    k_gemm1_scatter<<<mfmG + nbT, 256, 0, stream>>>(x, W1h, W1lo, b1_l, b1_r, buf1, N,
                                                    ei, E, rowptr, rank, adj, mfmG);

    // ---- conv1 ----
    conv1_fused<<<edgG, 128, 0, stream>>>(buf1, rowptr, adj, perm, att1, bias1,
                                          h1hi, h1lo, N);

    // ---- conv2 (pool accumulation fused into epilogue) ----
    gemm_mfma<128, false><<<mfmG, 256, 0, stream>>>(nullptr, h1hi, h1lo, N,
                                                    W2h, W2lo, b2_l, b2_r, buf2);
    conv2_fused<<<edgG, 128, 0, stream>>>(buf2, rowptr, adj, perm, att2, bias2,
                                          batch, gsum, N);

    // ---- MLP head ----
    pool_mlp<<<G, 256, 0, stream>>>(gsum, batch, fc1_w, fc1_b, fc2_w, fc2_b, out, N);
}